// Round 21
// baseline (34.786 us; speedup 1.0000x reference)
//
#include <hip/hip_runtime.h>
#include <math.h>

typedef _Float16 f16x8 __attribute__((ext_vector_type(8)));
typedef float f32x4 __attribute__((ext_vector_type(4)));

// ---------------------------------------------------------------------------
// qry (256c,16384px) f32; sup_x (5,256,128,128) f32; sup_y (5,128,128) f32.
// M=1280 protos, C=256. out (16384) f32.
// pred[px] = sum_m softmax(mask? d : NEG)_m * d_m, d = 20*<q_n[px], p_n[m]>.
// Identity: sum_c q_n[c] = 0 => MFMA on RAW pooled x (f16); epilogue
// d = alpha[m]*acc. Fixed-max softmax e = mk*exp(d-20); masked -> exactly 0.
// R20: active-proto compaction (mode 0 keeps ~640/1280) -> ~5 tiles.
// R21: qry -> REGISTERS (not LDS): frees buf0 from cycle 0 so tile-0 gather
// staging issues right after the compaction scatter and overlaps the whole
// stats/qs-write prologue; one fewer barrier; vmcnt over-drain fixed.
// pro_raw LINEAR; gather-stage applies row indirection + XOR swizzle on the
// per-lane GLOBAL source address (LDS dest linear; read path unchanged).
// ---------------------------------------------------------------------------

__global__ __launch_bounds__(256) void pool_kernel(const float* __restrict__ sup_x,
                                                   const float* __restrict__ sup_y,
                                                   _Float16* __restrict__ pro_raw,
                                                   float* __restrict__ psum,
                                                   float* __restrict__ yv_ws) {
    const int b = blockIdx.x, t = threadIdx.x;
    if (b < 640) {
        __shared__ float hs[8192];          // 32 KB: [run 256][lane 32] h-4sums
        __shared__ float xa[16][33];        // [gx][c] pooled values, padded
        const int s = b >> 7, rem = b & 127;
        const int gy = rem >> 3, cq = rem & 7;
        const float* base = sup_x + ((size_t)(s * 256 + cq * 32) * 128 + gy * 8) * 128;
#pragma unroll 8
        for (int i = 0; i < 32; ++i) {
            const int run = i * 8 + (t >> 5);
            const float4 v = *(const float4*)(base + ((size_t)(run >> 3) * 128 + (run & 7)) * 128 + (t & 31) * 4);
            hs[i * 256 + t] = v.x + v.y + v.z + v.w;
        }
        __syncthreads();
#pragma unroll
        for (int e0 = 0; e0 < 2; ++e0) {    // entry e = (c<<4)|gx
            const int e = e0 * 256 + t;
            const int c = e >> 4, gx = e & 15;
            float sum = 0.f;
#pragma unroll
            for (int r = 0; r < 8; ++r)
                sum += hs[(c * 8 + r) * 32 + gx * 2] + hs[(c * 8 + r) * 32 + gx * 2 + 1];
            xa[gx][c] = sum * (1.f / 64.f);
        }
        __syncthreads();
        const int mbase = s * 256 + gy * 16;
        if (t < 64) {                        // write 16m x 4 chunks f16 LINEAR
            const int gx = t >> 2, gi = t & 3;
            const int m = mbase + gx;
            const int g = cq * 4 + gi;
            f16x8 hv;
#pragma unroll
            for (int j = 0; j < 8; ++j) hv[j] = (_Float16)xa[gx][gi * 8 + j];
            *(f16x8*)(pro_raw + (size_t)m * 256 + (g << 3)) = hv;
        } else if (t < 80) {                 // partial stats over this block's 32 c
            const int gx = t - 64;
            float s1 = 0.f, s2 = 0.f;
#pragma unroll
            for (int c = 0; c < 32; ++c) { const float x = xa[gx][c]; s1 += x; s2 += x * x; }
            const int m = mbase + gx;
            psum[m * 16 + cq * 2]     = s1;
            psum[m * 16 + cq * 2 + 1] = s2;
        }
    } else {
        const int r = b - 640;
        const int gy = t >> 4, gx = t & 15;
        const float* base = sup_y + r * 16384 + gy * 1024 + gx * 8;
        float sum = 0.f;
#pragma unroll
        for (int rr = 0; rr < 8; ++rr) {
            const float4 a = *(const float4*)(base + rr * 128);
            const float4 bb = *(const float4*)(base + rr * 128 + 4);
            sum += a.x + a.y + a.z + a.w + bb.x + bb.y + bb.z + bb.w;
        }
        yv_ws[r * 256 + t] = sum * (1.f / 64.f);
    }
}

__device__ __forceinline__ void gload_lds16h(const _Float16* g, _Float16* l) {
    __builtin_amdgcn_global_load_lds((const __attribute__((address_space(1))) unsigned int*)g,
                                     (__attribute__((address_space(3))) unsigned int*)l,
                                     16, 0, 0);
}

// gather-stage one compacted 128-row tile: wave w stages ITS OWN 16 rows.
// Source address carries row indirection (idxc) AND the XOR swizzle; LDS
// dest is linear.
__device__ __forceinline__ void stage_gather(const _Float16* __restrict__ pro_raw,
                                             const unsigned short* __restrict__ idxc,
                                             int tb, _Float16* dst, int w, int l) {
#pragma unroll
    for (int i = 0; i < 8; ++i) {
        const int off = w * 4096 + i * 512 + l * 8;   // elements, linear in l
        const int rowp = off >> 8;                    // w*16 + i*2 + (l>>5)
        const int m = idxc[tb + rowp];
        const int sc = (l & 31) ^ (rowp & 7);         // swizzled source chunk
        gload_lds16h(pro_raw + (size_t)m * 256 + (sc << 3), dst + off);
    }
}

// compute one compacted 128-row tile: wave owns rows w*16..w*16+15.
__device__ __forceinline__ void compute_tile(const _Float16* __restrict__ pb,
                                             const float* __restrict__ alfc,
                                             int tilebase, int NA,
                                             const f16x8 (&bfr)[4][8],
                                             int row, int ln7, int lq, int w,
                                             float (&Sa)[4], float (&Wa)[4]) {
    f32x4 acc[4];
#pragma unroll
    for (int p = 0; p < 4; ++p) acc[p] = (f32x4){0.f, 0.f, 0.f, 0.f};
#pragma unroll
    for (int ks = 0; ks < 8; ++ks) {
        const int ch = (ks * 4 + lq) ^ ln7;          // bank-correct swizzle
        const f16x8 a = *(const f16x8*)(pb + row * 256 + ch * 8);
#pragma unroll
        for (int p = 0; p < 4; ++p)
            acc[p] = __builtin_amdgcn_mfma_f32_16x16x32_f16(a, bfr[p][ks], acc[p], 0, 0, 0);
    }
    const int jb = tilebase + w * 16 + lq * 4;
    const f32x4 av = *(const f32x4*)(alfc + jb);
#pragma unroll
    for (int p = 0; p < 4; ++p) {
        float ssum = 0.f, wsum = 0.f;
#pragma unroll
        for (int r = 0; r < 4; ++r) {
            const float d = av[r] * acc[p][r];
            const float mk = (jb + r < NA) ? 1.f : 0.f;   // padding -> exactly 0
            const float e = mk * __expf(d - 20.f);
            ssum += e; wsum += e * d;
        }
        Sa[p] += ssum; Wa[p] += wsum;
    }
}

// K2: 256 blocks x 512 thr (8 waves, 1 block/CU). qry in REGISTERS; compacted
// proto pipeline with early tile-0 staging.
__global__ __launch_bounds__(512, 2) void main_kernel(const float* __restrict__ qry,
                                                      const _Float16* __restrict__ pro_raw,
                                                      const float* __restrict__ psum,
                                                      const float* __restrict__ yv_ws,
                                                      float* __restrict__ out) {
    __shared__ __align__(16) _Float16 arena[65536];   // 128 KB: buf0 | buf1(qs)
    __shared__ __align__(16) float alfc[1408];        // compacted alpha (pad 0)
    __shared__ unsigned short idxc[1408];             // compacted m (pad 0)
    __shared__ int tot_s[20];
    __shared__ float scr[1024];
    __shared__ float2 stats[64];
    __shared__ int iflags[2];

    _Float16*  buf0 = arena;                // [0,64K)   free from cycle 0
    _Float16*  buf1 = arena + 32768;        // [64K,128K)
    _Float16*  qs   = arena + 32768;        // overlays buf1 [64K,96K)
    float*     red  = (float*)arena;        // 16 KB (epilogue, overlays buf0)

    const int t = threadIdx.x;
    const int w = t >> 6, l = t & 63;
    const int ln = l & 15, lq = l >> 4;
    const int ln7 = ln & 7;
    const int px0 = blockIdx.x * 64;

    if (t < 2) iflags[t] = 0;
    for (int i = t; i < 1408; i += 512) { alfc[i] = 0.f; idxc[i] = 0; }

    // ---- qry -> registers: thread (w,l) holds channels w*32..+31 of px l ----
    float qv[32];
#pragma unroll
    for (int j = 0; j < 32; ++j)
        qv[j] = qry[(size_t)(w * 32 + j) * 16384 + px0 + l];

    // ---- alpha[m] (regs) + mask flags (m = t, t+512, t+1024) ----
    float alf3[3], yv3[3];
    int f0 = 0, f1 = 0;
#pragma unroll
    for (int k = 0; k < 3; ++k) {
        const int m = t + k * 512;
        if (m < 1280) {
            float S1 = 0.f, S2 = 0.f;
            const f32x4* pp = (const f32x4*)(psum + m * 16);
#pragma unroll
            for (int u = 0; u < 4; ++u) {
                const f32x4 p = pp[u];
                S1 += p[0] + p[2]; S2 += p[1] + p[3];
            }
            alf3[k] = 20.f / fmaxf(sqrtf(fmaxf(S2 - S1 * S1 * (1.f / 256.f), 0.f)), 1e-4f);
            const float y = yv_ws[m];
            yv3[k] = y;
            if (y > 0.5f) f0 = 1;
            if (y > 0.1f) f1 = 1;
        }
    }
    if (f0) atomicOr(&iflags[0], 1);
    if (f1) atomicOr(&iflags[1], 1);
    __syncthreads();   // B1: flags final, padding zeros visible

    // ---- ballot compaction counts + per-px stats partials ----
    const int mode = iflags[0] ? 0 : (iflags[1] ? 1 : 2);
    int mk3[3] = {0, 0, 0}, pos3[3];
#pragma unroll
    for (int k = 0; k < 3; ++k) {
        const int m = t + k * 512;
        if (m < 1280) {   // wave-uniform guard
            const int mk = (mode == 0) ? (yv3[k] > 0.5f) : (mode == 1) ? (yv3[k] > 0.1f) : 1;
            mk3[k] = mk;
            const unsigned long long bal = __ballot(mk);
            pos3[k] = (int)__popcll(bal & ((1ull << l) - 1ull));
            if (l == 0) tot_s[k * 8 + w] = (int)__popcll(bal);
        }
    }
    {
        float s1 = 0.f, s2 = 0.f;
#pragma unroll
        for (int j = 0; j < 32; ++j) { s1 += qv[j]; s2 += qv[j] * qv[j]; }
        scr[w * 64 + l] = s1;
        scr[512 + w * 64 + l] = s2;
    }
    __syncthreads();   // B2: tot_s + scr ready

    // ---- prefix over 20 chunks (uniform) + scatter; stats finalize ----
    int NA;
    {
        int run = 0, base3[3] = {0, 0, 0};
#pragma unroll
        for (int c = 0; c < 20; ++c) {
#pragma unroll
            for (int k = 0; k < 3; ++k) if (c == k * 8 + w) base3[k] = run;
            run += tot_s[c];
        }
        NA = run;
#pragma unroll
        for (int k = 0; k < 3; ++k) {
            if (mk3[k]) {
                const int j = base3[k] + pos3[k];
                idxc[j] = (unsigned short)(t + k * 512);
                alfc[j] = alf3[k];
            }
        }
    }
    if (t < 64) {
        float S1 = 0.f, S2 = 0.f;
#pragma unroll
        for (int q = 0; q < 8; ++q) { S1 += scr[q * 64 + t]; S2 += scr[512 + q * 64 + t]; }
        const float mu = S1 * (1.f / 256.f);
        const float nrm = sqrtf(fmaxf(S2 - 256.f * mu * mu, 0.f));
        stats[t] = make_float2(mu, 1.f / fmaxf(nrm, 1e-4f));
    }
    __syncthreads();   // B3: idxc/alfc + stats ready

    const int ntiles = (NA + 127) >> 7;

    // ---- EARLY: stage tile 0 (buf0 was never used) -> overlaps qs + hoist ----
    stage_gather(pro_raw, idxc, 0, buf0, w, l);

    // ---- qs write from registers (swizzled f16) ----
    {
        const float2 st = stats[l];
#pragma unroll
        for (int u = 0; u < 4; ++u) {
            const int g = w * 4 + u;
            f16x8 hv;
#pragma unroll
            for (int j = 0; j < 8; ++j)
                hv[j] = (_Float16)((qv[u * 8 + j] - st.x) * st.y);
            *(f16x8*)(qs + l * 256 + ((g ^ (l & 7)) << 3)) = hv;
        }
    }
    __syncthreads();   // B4: qs ready

    f16x8 bfr[4][8];
#pragma unroll
    for (int p = 0; p < 4; ++p) {
        const int px = p * 16 + ln;
        const int sB = px & 7;
#pragma unroll
        for (int ks = 0; ks < 8; ++ks) {
            const int g = ks * 4 + lq;
            bfr[p][ks] = *(const f16x8*)(qs + px * 256 + ((g ^ sB) << 3));
        }
    }
    __syncthreads();   // B5: all waves done reading qs -> buf1 region free

    if (ntiles > 1) stage_gather(pro_raw, idxc, 128, buf1, w, l);

    const int row = w * 16 + ln;
    float Sa[4] = {0.f, 0.f, 0.f, 0.f}, Wa[4] = {0.f, 0.f, 0.f, 0.f};

#pragma unroll 1
    for (int tile = 0; tile < ntiles; ++tile) {
        if (tile < ntiles - 1) asm volatile("s_waitcnt vmcnt(8)" ::: "memory");
        else                   asm volatile("s_waitcnt vmcnt(0)" ::: "memory");
        compute_tile((tile & 1) ? buf1 : buf0, alfc, tile * 128, NA,
                     bfr, row, ln7, lq, w, Sa, Wa);
        if (tile + 2 < ntiles) {
            // all ds_reads of this buffer retired before we overwrite it
            asm volatile("s_waitcnt lgkmcnt(0)" ::: "memory");
            __builtin_amdgcn_sched_barrier(0);
            stage_gather(pro_raw, idxc, (tile + 2) * 128, (tile & 1) ? buf1 : buf0, w, l);
        }
    }

    __syncthreads();   // all waves done with buffers -> red overlay safe
#pragma unroll
    for (int p = 0; p < 4; ++p) {
        const int px = p * 16 + ln;
        const int slot = (w * 4 + lq + px) & 31;
        red[px * 32 + slot] = Sa[p];
        red[2048 + px * 32 + slot] = Wa[p];
    }
    __syncthreads();
    if (t < 64) {
        float S = 0.f, W = 0.f;
        for (int s = 0; s < 32; ++s) {
            const int slot = (s + t) & 31;
            S += red[t * 32 + slot];
            W += red[2048 + t * 32 + slot];
        }
        out[px0 + t] = W / S;
    }
}

extern "C" void kernel_launch(void* const* d_in, const int* in_sizes, int n_in,
                              void* d_out, int out_size, void* d_ws, size_t ws_size,
                              hipStream_t stream) {
    const float* qry   = (const float*)d_in[0];   // 256*16384
    const float* sup_x = (const float*)d_in[1];   // 5*256*16384
    const float* sup_y = (const float*)d_in[2];   // 5*16384
    float* out = (float*)d_out;                   // 16384

    char* ws = (char*)d_ws;
    _Float16*  pro_raw = (_Float16*)ws;           ws += 1280 * 256 * 2;   // 640 KB
    float*     psum    = (float*)ws;              ws += 1280 * 16 * 4;    // 80 KB
    float*     yv_ws   = (float*)ws;              /* 5 KB */

    pool_kernel<<<645, 256, 0, stream>>>(sup_x, sup_y, pro_raw, psum, yv_ws);
    main_kernel<<<256, 512, 0, stream>>>(qry, pro_raw, psum, yv_ws, out);
}